// Round 7
// baseline (367.404 us; speedup 1.0000x reference)
//
#include <hip/hip_runtime.h>
#include <hip/hip_bf16.h>

// Problem constants
static constexpr int N_   = 100000;
static constexpr int E_   = 1600000;
static constexpr int FIN_ = 128;
static constexpr int DIM_ = 32;
static constexpr int NC_  = 40;
static constexpr int NB_BKT = (N_ + 127) / 128;   // 782 buckets of 128 dst nodes
static constexpr int NCHUNK = 256;                // edge chunks
static constexpr int EPC    = E_ / NCHUNK;        // 6250 edges per chunk (exact)
static constexpr int PROJ_NB = N_ / 32;           // 3125 proj blocks

__device__ __forceinline__ int edge_at(const void* e, int is64, long long i) {
    return is64 ? (int)((const long long*)e)[i] : ((const int*)e)[i];
}

__device__ __forceinline__ float bflo(unsigned u) { return __uint_as_float(u << 16); }
__device__ __forceinline__ float bfhi(unsigned u) { return __uint_as_float(u & 0xffff0000u); }

// Per-block edge dtype detection (reference says int64; JAX x64-off gives int32;
// int32 read as int64 -> garbage high words -> out of [0,N) w.h.p.)
#define DETECT_FLAG(edge, sflag)                                        \
    if (threadIdx.x < 64) {                                             \
        const long long* p_ = (const long long*)(edge);                 \
        long long v_ = p_[threadIdx.x];                                 \
        bool bad_ = (v_ < 0 || v_ >= (long long)N_);                    \
        unsigned long long m_ = __ballot(bad_);                         \
        if (threadIdx.x == 0) sflag = (m_ == 0ull) ? 1 : 0;             \
    }                                                                   \
    __syncthreads();

// ---------------------------------------------------------------------------
// Build 1: per-chunk bucket histogram in LDS -> ghist[b][k]
// ---------------------------------------------------------------------------
__global__ __launch_bounds__(256) void chist_kernel(const void* __restrict__ edge,
                                                    int* __restrict__ ghist) {
    __shared__ int lh[NB_BKT];
    __shared__ int sflag;
    DETECT_FLAG(edge, sflag)
    for (int i = threadIdx.x; i < NB_BKT; i += 256) lh[i] = 0;
    __syncthreads();
    int f = sflag;
    int b = blockIdx.x;
    int end = b * EPC + EPC;
    for (int e = b * EPC + threadIdx.x; e < end; e += 256) {
        int d = edge_at(edge, f, (long long)E_ + e);
        atomicAdd(&lh[d >> 7], 1);           // LDS int atomic
    }
    __syncthreads();
    for (int i = threadIdx.x; i < NB_BKT; i += 256) ghist[b * NB_BKT + i] = lh[i];
}

// ---------------------------------------------------------------------------
// Build 2: column scan of ghist -> gcurT[k][b] + bcnt[k]; LAST block also
// scans bucket totals -> bbase + offs[N] (device-scope ticket pattern).
// ---------------------------------------------------------------------------
__global__ __launch_bounds__(256) void colscan_kernel(const int* __restrict__ ghist,
                                                      int* __restrict__ gcurT,
                                                      int* __restrict__ bcnt,
                                                      int* __restrict__ bbase,
                                                      int* __restrict__ offs,
                                                      int* __restrict__ done) {
    __shared__ int a[256];
    __shared__ int lastFlag;
    int k = blockIdx.x, tid = threadIdx.x;
    int v = ghist[tid * NB_BKT + k];
    a[tid] = v;
    __syncthreads();
    for (int off = 1; off < 256; off <<= 1) {
        int t = a[tid] + ((tid >= off) ? a[tid - off] : 0);
        __syncthreads(); a[tid] = t; __syncthreads();
    }
    gcurT[k * NCHUNK + tid] = a[tid] - v;     // exclusive within column
    if (tid == 255) {
        bcnt[k] = a[255];                     // column total
        __threadfence();                      // release bcnt before ticket
        int old = atomicAdd(done, 1);
        lastFlag = (old == NB_BKT - 1) ? 1 : 0;
    }
    __syncthreads();
    if (lastFlag) {
        __threadfence();                      // acquire other blocks' bcnt
        int b4[4]; int base4 = tid * 4; int s = 0;
#pragma unroll
        for (int j = 0; j < 4; ++j) { int i = base4 + j; b4[j] = (i < NB_BKT) ? bcnt[i] : 0; s += b4[j]; }
        __syncthreads();                      // a[] reuse safe
        a[tid] = s;
        __syncthreads();
        for (int off = 1; off < 256; off <<= 1) {
            int t = a[tid] + ((tid >= off) ? a[tid - off] : 0);
            __syncthreads(); a[tid] = t; __syncthreads();
        }
        int g = a[tid] - s;
#pragma unroll
        for (int j = 0; j < 4; ++j) { int i = base4 + j; if (i < NB_BKT) bbase[i] = g; g += b4[j]; }
        if (tid == 255) offs[N_] = a[255];    // == E_
    }
}

// ---------------------------------------------------------------------------
// Build 3: deterministic scatter into bucket regions; cursors in LDS.
// ---------------------------------------------------------------------------
__global__ __launch_bounds__(256) void dscatter_kernel(const void* __restrict__ edge,
                                                       const int* __restrict__ bbase,
                                                       const int* __restrict__ gcurT,
                                                       int* __restrict__ packed) {
    __shared__ int cur[NB_BKT];
    __shared__ int sflag;
    DETECT_FLAG(edge, sflag)
    int b = blockIdx.x, tid = threadIdx.x;
    for (int k = tid; k < NB_BKT; k += 256) cur[k] = bbase[k] + gcurT[k * NCHUNK + b];
    __syncthreads();
    int f = sflag;
    int end = b * EPC + EPC;
    for (int e = b * EPC + tid; e < end; e += 256) {
        int s = edge_at(edge, f, e);
        int d = edge_at(edge, f, (long long)E_ + e);
        int pos = atomicAdd(&cur[d >> 7], 1);     // LDS int atomic
        packed[pos] = s | ((d & 127) << 17);      // N < 2^17
    }
}

// ---------------------------------------------------------------------------
// Build 4 ∥ proj: blocks [0,782): per-bucket counting sort -> offs[] + csr[];
// blocks [782, 782+3125): yh = bf16(x @ w1a). Independent work, one dispatch.
// ---------------------------------------------------------------------------
__global__ __launch_bounds__(256) void fat_kernel(const int* __restrict__ bcnt,
                                                  const int* __restrict__ bbase,
                                                  const int* __restrict__ packed,
                                                  int* __restrict__ offs,
                                                  int* __restrict__ csr,
                                                  const float* __restrict__ x,
                                                  const float* __restrict__ w,
                                                  __hip_bfloat16* __restrict__ yh) {
    __shared__ __align__(16) char smem[32768];
    int tid = threadIdx.x;
    if (blockIdx.x < NB_BKT) {
        // ---- bsort ----
        int* c   = (int*)smem;          // 128
        int* cur = (int*)smem + 128;    // 128
        int b = blockIdx.x;
        int beg = bbase[b], cnt = bcnt[b];
        if (tid < 128) c[tid] = 0;
        __syncthreads();
        for (int i = tid; i < cnt; i += 256)
            atomicAdd(&c[packed[beg + i] >> 17], 1);
        __syncthreads();
        int myv = (tid < 128) ? c[tid] : 0;
        for (int off = 1; off < 128; off <<= 1) {
            int t = 0;
            if (tid < 128) t = c[tid] + ((tid >= off) ? c[tid - off] : 0);
            __syncthreads();
            if (tid < 128) c[tid] = t;
            __syncthreads();
        }
        if (tid < 128) {
            int ex = c[tid] - myv;
            cur[tid] = ex;
            int node = b * 128 + tid;
            if (node < N_) offs[node] = beg + ex;
        }
        __syncthreads();
        for (int i = tid; i < cnt; i += 256) {
            int v = packed[beg + i];
            int p = atomicAdd(&cur[v >> 17], 1);
            csr[beg + p] = v & 0x1FFFF;
        }
    } else {
        // ---- proj1: 32 nodes per block ----
        float* wsm = (float*)smem;               // 128*32 = 16 KB
        float* xs  = (float*)(smem + 16384);     // 32*128 = 16 KB
        const float4* w4 = (const float4*)w;
        float4* ws4 = (float4*)wsm;
        for (int i = tid; i < FIN_ * DIM_ / 4; i += 256) ws4[i] = w4[i];

        int nodeBase = (blockIdx.x - NB_BKT) * 32;
        const float4* x4 = (const float4*)(x + (size_t)nodeBase * FIN_);
        float4* xs4 = (float4*)xs;
        for (int i = tid; i < 32 * FIN_ / 4; i += 256) xs4[i] = x4[i];
        __syncthreads();

        int d = tid & 31, ns = tid >> 5;
        for (int rep = 0; rep < 4; ++rep) {
            int node = ns + rep * 8;
            float acc = 0.f;
#pragma unroll 4
            for (int k = 0; k < FIN_; ++k) acc += xs[node * FIN_ + k] * wsm[k * DIM_ + d];
            yh[(size_t)(nodeBase + node) * DIM_ + d] = __float2bfloat16(acc);
        }
    }
}

// ---------------------------------------------------------------------------
// Gather: 4 lanes x 16B (uint4) per 64B row -> 16 lines in flight per
// wave-instruction; 4-wide unroll. 8 float accumulators per lane.
// ---------------------------------------------------------------------------
__device__ __forceinline__ void gather_row4(const int* __restrict__ csr,
                                            const char* __restrict__ vb,
                                            int beg, int end, int loff, float* acc) {
    int i = beg;
    for (; i + 3 < end; i += 4) {
        int s0 = csr[i], s1 = csr[i + 1], s2 = csr[i + 2], s3 = csr[i + 3];
        uint4 u0 = *(const uint4*)(vb + (((size_t)s0) << 6) + loff);
        uint4 u1 = *(const uint4*)(vb + (((size_t)s1) << 6) + loff);
        uint4 u2 = *(const uint4*)(vb + (((size_t)s2) << 6) + loff);
        uint4 u3 = *(const uint4*)(vb + (((size_t)s3) << 6) + loff);
        acc[0] += (bflo(u0.x) + bflo(u1.x)) + (bflo(u2.x) + bflo(u3.x));
        acc[1] += (bfhi(u0.x) + bfhi(u1.x)) + (bfhi(u2.x) + bfhi(u3.x));
        acc[2] += (bflo(u0.y) + bflo(u1.y)) + (bflo(u2.y) + bflo(u3.y));
        acc[3] += (bfhi(u0.y) + bfhi(u1.y)) + (bfhi(u2.y) + bfhi(u3.y));
        acc[4] += (bflo(u0.z) + bflo(u1.z)) + (bflo(u2.z) + bflo(u3.z));
        acc[5] += (bfhi(u0.z) + bfhi(u1.z)) + (bfhi(u2.z) + bfhi(u3.z));
        acc[6] += (bflo(u0.w) + bflo(u1.w)) + (bflo(u2.w) + bflo(u3.w));
        acc[7] += (bfhi(u0.w) + bfhi(u1.w)) + (bfhi(u2.w) + bfhi(u3.w));
    }
    for (; i < end; ++i) {
        int s0 = csr[i];
        uint4 u0 = *(const uint4*)(vb + (((size_t)s0) << 6) + loff);
        acc[0] += bflo(u0.x); acc[1] += bfhi(u0.x);
        acc[2] += bflo(u0.y); acc[3] += bfhi(u0.y);
        acc[4] += bflo(u0.z); acc[5] += bfhi(u0.z);
        acc[6] += bflo(u0.w); acc[7] += bfhi(u0.w);
    }
}

// ---------------------------------------------------------------------------
// Fused 1: gather over bf16 y (64 nodes/block), then u=relu(agg+y+b1a);
// hb=bn1(relu(u@w1b+b1b)); zh=bf16(hb@w2a).
// ---------------------------------------------------------------------------
__global__ __launch_bounds__(256) void aggmlp1_kernel(const int* __restrict__ offs,
                                                      const int* __restrict__ csr,
                                                      const __hip_bfloat16* __restrict__ yh,
                                                      const float* __restrict__ b1a,
                                                      const float* __restrict__ w1b,
                                                      const float* __restrict__ b1b,
                                                      const float* __restrict__ g1,
                                                      const float* __restrict__ be1,
                                                      const float* __restrict__ m1,
                                                      const float* __restrict__ v1,
                                                      const float* __restrict__ w2a,
                                                      __hip_bfloat16* __restrict__ zh) {
    __shared__ float A[64 * 33];
    __shared__ float B[64 * 33];
    __shared__ float w1s[DIM_ * DIM_];
    __shared__ float w2s[DIM_ * DIM_];
    int tid = threadIdx.x;
    for (int i = tid; i < DIM_ * DIM_; i += 256) { w1s[i] = w1b[i]; w2s[i] = w2a[i]; }

    // --- gather phase: 4 lanes per node, 64 nodes/block ---
    int nl = tid >> 2, lane = tid & 3;
    int node = blockIdx.x * 64 + nl;
    int beg = 0, end = 0;
    if (node < N_) { beg = offs[node]; end = offs[node + 1]; }
    float acc[8] = {0.f, 0.f, 0.f, 0.f, 0.f, 0.f, 0.f, 0.f};
    gather_row4(csr, (const char*)yh, beg, end, lane << 4, acc);
    {
        float* p = &A[nl * 33 + lane * 8];
#pragma unroll
        for (int j = 0; j < 8; ++j) p[j] = acc[j];
    }
    __syncthreads();

    int d = tid & 31, ng = tid >> 5;
    size_t gbase = (size_t)blockIdx.x * 64 * DIM_;

    // u = relu(agg + y + b1a)
#pragma unroll
    for (int r = 0; r < 8; ++r) {
        int n = r * 8 + ng;
        if (blockIdx.x * 64 + n < N_) {
            float yv = __bfloat162float(yh[gbase + n * DIM_ + d]);
            A[n * 33 + d] = fmaxf(A[n * 33 + d] + yv + b1a[d], 0.f);
        }
    }
    __syncthreads();

    float sc1 = g1[d] * rsqrtf(v1[d] + 1e-5f);
    float sh1 = be1[d] - m1[d] * sc1;

    // hb = bn1(relu(u @ w1b + b1b))
#pragma unroll
    for (int r = 0; r < 8; ++r) {
        int n = r * 8 + ng;
        float s = b1b[d];
#pragma unroll
        for (int k = 0; k < DIM_; ++k) s += A[n * 33 + k] * w1s[k * DIM_ + d];
        B[n * 33 + d] = fmaxf(s, 0.f) * sc1 + sh1;
    }
    __syncthreads();

    // z = hb @ w2a -> bf16
#pragma unroll
    for (int r = 0; r < 8; ++r) {
        int n = r * 8 + ng;
        float s = 0.f;
#pragma unroll
        for (int k = 0; k < DIM_; ++k) s += B[n * 33 + k] * w2s[k * DIM_ + d];
        if (blockIdx.x * 64 + n < N_) zh[gbase + n * DIM_ + d] = __float2bfloat16(s);
    }
}

// ---------------------------------------------------------------------------
// Fused 2: gather over bf16 z, then u=relu(agg+z+b2a); hb=bn2(u@w2b+b2b);
// f=relu(hb@fc1w+fc1b); logits=f@fc2w+fc2b; out=log_softmax(logits).
// wC loaded over B's LDS after B is dead.
// ---------------------------------------------------------------------------
__global__ __launch_bounds__(256) void aggmlp2_kernel(const int* __restrict__ offs,
                                                      const int* __restrict__ csr,
                                                      const __hip_bfloat16* __restrict__ zh,
                                                      const float* __restrict__ b2a,
                                                      const float* __restrict__ w2b,
                                                      const float* __restrict__ b2b,
                                                      const float* __restrict__ g2,
                                                      const float* __restrict__ be2,
                                                      const float* __restrict__ m2,
                                                      const float* __restrict__ v2,
                                                      const float* __restrict__ f1w,
                                                      const float* __restrict__ f1b,
                                                      const float* __restrict__ f2w,
                                                      const float* __restrict__ f2b,
                                                      float* __restrict__ out) {
    __shared__ float A[64 * 33];
    __shared__ float BC[64 * 33];    // phases: B (hb); then wC (DIM*NC = 1280 <= 2112)
    __shared__ float wA[DIM_ * DIM_];
    __shared__ float wB[DIM_ * DIM_];
    int tid = threadIdx.x;
    for (int i = tid; i < DIM_ * DIM_; i += 256) { wA[i] = w2b[i]; wB[i] = f1w[i]; }

    // --- gather phase ---
    int nl = tid >> 2, lane = tid & 3;
    int node = blockIdx.x * 64 + nl;
    int beg = 0, end = 0;
    if (node < N_) { beg = offs[node]; end = offs[node + 1]; }
    float acc[8] = {0.f, 0.f, 0.f, 0.f, 0.f, 0.f, 0.f, 0.f};
    gather_row4(csr, (const char*)zh, beg, end, lane << 4, acc);
    {
        float* p = &A[nl * 33 + lane * 8];
#pragma unroll
        for (int j = 0; j < 8; ++j) p[j] = acc[j];
    }
    __syncthreads();

    int d = tid & 31, ng = tid >> 5;
    size_t gbase = (size_t)blockIdx.x * 64 * DIM_;

    // u2 = relu(agg + z + b2a)
#pragma unroll
    for (int r = 0; r < 8; ++r) {
        int n = r * 8 + ng;
        if (blockIdx.x * 64 + n < N_) {
            float zv = __bfloat162float(zh[gbase + n * DIM_ + d]);
            A[n * 33 + d] = fmaxf(A[n * 33 + d] + zv + b2a[d], 0.f);
        }
    }
    __syncthreads();

    float sc2 = g2[d] * rsqrtf(v2[d] + 1e-5f);
    float sh2 = be2[d] - m2[d] * sc2;

    // hb = bn2(u2 @ w2b + b2b)   (no relu between conv2 and bn2)
#pragma unroll
    for (int r = 0; r < 8; ++r) {
        int n = r * 8 + ng;
        float s = b2b[d];
#pragma unroll
        for (int k = 0; k < DIM_; ++k) s += A[n * 33 + k] * wA[k * DIM_ + d];
        BC[n * 33 + d] = s * sc2 + sh2;
    }
    __syncthreads();

    // f = relu(hb @ fc1w + fc1b) -> overwrite A
#pragma unroll
    for (int r = 0; r < 8; ++r) {
        int n = r * 8 + ng;
        float s = f1b[d];
#pragma unroll
        for (int k = 0; k < DIM_; ++k) s += BC[n * 33 + k] * wB[k * DIM_ + d];
        A[n * 33 + d] = fmaxf(s, 0.f);
    }
    __syncthreads();
    // B dead -> load wC
    for (int i = tid; i < DIM_ * NC_; i += 256) BC[i] = f2w[i];
    __syncthreads();

    // logits + log_softmax (thread d owns col d and col 32+(d&7))
    int c2 = 32 + (d & 7);
#pragma unroll
    for (int r = 0; r < 8; ++r) {
        int n = r * 8 + ng;
        float l0 = f2b[d];
        float l1 = f2b[c2];
#pragma unroll
        for (int k = 0; k < DIM_; ++k) {
            float fv = A[n * 33 + k];
            l0 += fv * BC[k * NC_ + d];
            l1 += fv * BC[k * NC_ + c2];
        }
        float mx = fmaxf(l0, l1);
#pragma unroll
        for (int off = 16; off; off >>= 1) mx = fmaxf(mx, __shfl_xor(mx, off));
        float se = __expf(l0 - mx) + ((d < 8) ? __expf(l1 - mx) : 0.f);
#pragma unroll
        for (int off = 16; off; off >>= 1) se += __shfl_xor(se, off);
        float lse = mx + __logf(se);
        int gn = blockIdx.x * 64 + n;
        if (gn < N_) {
            size_t ob = (size_t)gn * NC_;
            out[ob + d] = l0 - lse;
            if (d < 8) out[ob + 32 + d] = l1 - lse;
        }
    }
}

// ---------------------------------------------------------------------------
extern "C" void kernel_launch(void* const* d_in, const int* in_sizes, int n_in,
                              void* d_out, int out_size, void* d_ws, size_t ws_size,
                              hipStream_t stream) {
    const float* x   = (const float*)d_in[0];
    const void*  edg = d_in[1];
    const float* w1a = (const float*)d_in[2];
    const float* b1a = (const float*)d_in[3];
    const float* w1b = (const float*)d_in[4];
    const float* b1b = (const float*)d_in[5];
    const float* w2a = (const float*)d_in[6];
    const float* b2a = (const float*)d_in[7];
    const float* w2b = (const float*)d_in[8];
    const float* b2b = (const float*)d_in[9];
    const float* g1  = (const float*)d_in[10];
    const float* be1 = (const float*)d_in[11];
    const float* m1  = (const float*)d_in[12];
    const float* v1  = (const float*)d_in[13];
    const float* g2  = (const float*)d_in[14];
    const float* be2 = (const float*)d_in[15];
    const float* m2  = (const float*)d_in[16];
    const float* v2  = (const float*)d_in[17];
    const float* f1w = (const float*)d_in[18];
    const float* f1b = (const float*)d_in[19];
    const float* f2w = (const float*)d_in[20];
    const float* f2b = (const float*)d_in[21];
    float* out = (float*)d_out;

    // Workspace layout (byte offsets, 128B-aligned)
    char* ws = (char*)d_ws;
    int* done   = (int*)ws;                      // 4 B (memset each launch)
    int* bcnt   = (int*)(ws + 256);              // 782 ints (pad 3328)
    int* bbase  = (int*)(ws + 3584);             // 782 ints (pad 3328)
    int* ghist  = (int*)(ws + 6912);             // 256*782 ints
    int* gcurT  = (int*)(ws + 807680);           // 782*256 ints
    int* offs   = (int*)(ws + 1608448);          // N+1 ints (pad 400128)
    int* packed = (int*)(ws + 2008576);          // E ints
    int* csr    = (int*)(ws + 8408576);          // E ints
    __hip_bfloat16* yh = (__hip_bfloat16*)(ws + 14808576);  // N*DIM bf16
    __hip_bfloat16* zh = (__hip_bfloat16*)(ws + 21208576);  // N*DIM bf16

    hipMemsetAsync(done, 0, 4, stream);

    // ---- Build per-node CSR (deterministic, no global atomics) ----
    chist_kernel<<<NCHUNK, 256, 0, stream>>>(edg, ghist);
    colscan_kernel<<<NB_BKT, 256, 0, stream>>>(ghist, gcurT, bcnt, bbase, offs, done);
    dscatter_kernel<<<NCHUNK, 256, 0, stream>>>(edg, bbase, gcurT, packed);
    fat_kernel<<<NB_BKT + PROJ_NB, 256, 0, stream>>>(bcnt, bbase, packed, offs, csr,
                                                     x, w1a, yh);

    // ---- Layer 1 (proj folded pre-aggregation) ----
    aggmlp1_kernel<<<(N_ + 63) / 64, 256, 0, stream>>>(offs, csr, yh, b1a, w1b, b1b,
                                                       g1, be1, m1, v1, w2a, zh);

    // ---- Layer 2 + head (w2a folded pre-aggregation) ----
    aggmlp2_kernel<<<(N_ + 63) / 64, 256, 0, stream>>>(offs, csr, zh, b2a, w2b, b2b,
                                                       g2, be2, m2, v2, f1w, f1b,
                                                       f2w, f2b, out);
}

// Round 8
// 360.171 us; speedup vs baseline: 1.0201x; 1.0201x over previous
//
#include <hip/hip_runtime.h>
#include <hip/hip_bf16.h>

// Problem constants
static constexpr int N_   = 100000;
static constexpr int E_   = 1600000;
static constexpr int FIN_ = 128;
static constexpr int DIM_ = 32;
static constexpr int NC_  = 40;
static constexpr int NB_BKT = (N_ + 127) / 128;   // 782 buckets of 128 dst nodes
static constexpr int NCHUNK = 256;                // edge chunks
static constexpr int EPC    = E_ / NCHUNK;        // 6250 edges per chunk (exact)
static constexpr int PROJ_NB = N_ / 32;           // 3125 proj blocks

__device__ __forceinline__ int edge_at(const void* e, int is64, long long i) {
    return is64 ? (int)((const long long*)e)[i] : ((const int*)e)[i];
}

__device__ __forceinline__ float bflo(unsigned u) { return __uint_as_float(u << 16); }
__device__ __forceinline__ float bfhi(unsigned u) { return __uint_as_float(u & 0xffff0000u); }

// Per-block edge dtype detection (reference says int64; JAX x64-off gives int32;
// int32 read as int64 -> garbage high words -> out of [0,N) w.h.p.)
#define DETECT_FLAG(edge, sflag)                                        \
    if (threadIdx.x < 64) {                                             \
        const long long* p_ = (const long long*)(edge);                 \
        long long v_ = p_[threadIdx.x];                                 \
        bool bad_ = (v_ < 0 || v_ >= (long long)N_);                    \
        unsigned long long m_ = __ballot(bad_);                         \
        if (threadIdx.x == 0) sflag = (m_ == 0ull) ? 1 : 0;             \
    }                                                                   \
    __syncthreads();

// ---------------------------------------------------------------------------
// Build 1: per-chunk bucket histogram in LDS -> ghist[b][k]
// ---------------------------------------------------------------------------
__global__ __launch_bounds__(256) void chist_kernel(const void* __restrict__ edge,
                                                    int* __restrict__ ghist) {
    __shared__ int lh[NB_BKT];
    __shared__ int sflag;
    DETECT_FLAG(edge, sflag)
    for (int i = threadIdx.x; i < NB_BKT; i += 256) lh[i] = 0;
    __syncthreads();
    int f = sflag;
    int b = blockIdx.x;
    int end = b * EPC + EPC;
    for (int e = b * EPC + threadIdx.x; e < end; e += 256) {
        int d = edge_at(edge, f, (long long)E_ + e);
        atomicAdd(&lh[d >> 7], 1);           // LDS int atomic
    }
    __syncthreads();
    for (int i = threadIdx.x; i < NB_BKT; i += 256) ghist[b * NB_BKT + i] = lh[i];
}

// ---------------------------------------------------------------------------
// Build 2: column scan of ghist -> gcurT[k][b] + bcnt[k]; LAST block also
// scans bucket totals -> bbase + offs[N] (device-scope ticket pattern).
// ---------------------------------------------------------------------------
__global__ __launch_bounds__(256) void colscan_kernel(const int* __restrict__ ghist,
                                                      int* __restrict__ gcurT,
                                                      int* __restrict__ bcnt,
                                                      int* __restrict__ bbase,
                                                      int* __restrict__ offs,
                                                      int* __restrict__ done) {
    __shared__ int a[256];
    __shared__ int lastFlag;
    int k = blockIdx.x, tid = threadIdx.x;
    int v = ghist[tid * NB_BKT + k];
    a[tid] = v;
    __syncthreads();
    for (int off = 1; off < 256; off <<= 1) {
        int t = a[tid] + ((tid >= off) ? a[tid - off] : 0);
        __syncthreads(); a[tid] = t; __syncthreads();
    }
    gcurT[k * NCHUNK + tid] = a[tid] - v;     // exclusive within column
    if (tid == 255) {
        bcnt[k] = a[255];                     // column total
        __threadfence();                      // release bcnt before ticket
        int old = atomicAdd(done, 1);
        lastFlag = (old == NB_BKT - 1) ? 1 : 0;
    }
    __syncthreads();
    if (lastFlag) {
        __threadfence();                      // acquire other blocks' bcnt
        int b4[4]; int base4 = tid * 4; int s = 0;
#pragma unroll
        for (int j = 0; j < 4; ++j) { int i = base4 + j; b4[j] = (i < NB_BKT) ? bcnt[i] : 0; s += b4[j]; }
        __syncthreads();
        a[tid] = s;
        __syncthreads();
        for (int off = 1; off < 256; off <<= 1) {
            int t = a[tid] + ((tid >= off) ? a[tid - off] : 0);
            __syncthreads(); a[tid] = t; __syncthreads();
        }
        int g = a[tid] - s;
#pragma unroll
        for (int j = 0; j < 4; ++j) { int i = base4 + j; if (i < NB_BKT) bbase[i] = g; g += b4[j]; }
        if (tid == 255) offs[N_] = a[255];    // == E_
    }
}

// ---------------------------------------------------------------------------
// Build 3: deterministic scatter into bucket regions; cursors in LDS.
// ---------------------------------------------------------------------------
__global__ __launch_bounds__(256) void dscatter_kernel(const void* __restrict__ edge,
                                                       const int* __restrict__ bbase,
                                                       const int* __restrict__ gcurT,
                                                       int* __restrict__ packed) {
    __shared__ int cur[NB_BKT];
    __shared__ int sflag;
    DETECT_FLAG(edge, sflag)
    int b = blockIdx.x, tid = threadIdx.x;
    for (int k = tid; k < NB_BKT; k += 256) cur[k] = bbase[k] + gcurT[k * NCHUNK + b];
    __syncthreads();
    int f = sflag;
    int end = b * EPC + EPC;
    for (int e = b * EPC + tid; e < end; e += 256) {
        int s = edge_at(edge, f, e);
        int d = edge_at(edge, f, (long long)E_ + e);
        int pos = atomicAdd(&cur[d >> 7], 1);     // LDS int atomic
        packed[pos] = s | ((d & 127) << 17);      // N < 2^17
    }
}

// ---------------------------------------------------------------------------
// Build 4 ∥ proj: blocks [0,782): per-bucket counting sort -> offs[] + csr[];
// blocks [782, 782+3125): yh = bf16(x @ w1a). Independent work, one dispatch.
// ---------------------------------------------------------------------------
__global__ __launch_bounds__(256) void fat_kernel(const int* __restrict__ bcnt,
                                                  const int* __restrict__ bbase,
                                                  const int* __restrict__ packed,
                                                  int* __restrict__ offs,
                                                  int* __restrict__ csr,
                                                  const float* __restrict__ x,
                                                  const float* __restrict__ w,
                                                  __hip_bfloat16* __restrict__ yh) {
    __shared__ __align__(16) char smem[32768];
    int tid = threadIdx.x;
    if (blockIdx.x < NB_BKT) {
        // ---- bsort ----
        int* c   = (int*)smem;          // 128
        int* cur = (int*)smem + 128;    // 128
        int b = blockIdx.x;
        int beg = bbase[b], cnt = bcnt[b];
        if (tid < 128) c[tid] = 0;
        __syncthreads();
        for (int i = tid; i < cnt; i += 256)
            atomicAdd(&c[packed[beg + i] >> 17], 1);
        __syncthreads();
        int myv = (tid < 128) ? c[tid] : 0;
        for (int off = 1; off < 128; off <<= 1) {
            int t = 0;
            if (tid < 128) t = c[tid] + ((tid >= off) ? c[tid - off] : 0);
            __syncthreads();
            if (tid < 128) c[tid] = t;
            __syncthreads();
        }
        if (tid < 128) {
            int ex = c[tid] - myv;
            cur[tid] = ex;
            int node = b * 128 + tid;
            if (node < N_) offs[node] = beg + ex;
        }
        __syncthreads();
        for (int i = tid; i < cnt; i += 256) {
            int v = packed[beg + i];
            int p = atomicAdd(&cur[v >> 17], 1);
            csr[beg + p] = v & 0x1FFFF;
        }
    } else {
        // ---- proj1: 32 nodes per block ----
        float* wsm = (float*)smem;               // 128*32 = 16 KB
        float* xs  = (float*)(smem + 16384);     // 32*128 = 16 KB
        const float4* w4 = (const float4*)w;
        float4* ws4 = (float4*)wsm;
        for (int i = tid; i < FIN_ * DIM_ / 4; i += 256) ws4[i] = w4[i];

        int nodeBase = (blockIdx.x - NB_BKT) * 32;
        const float4* x4 = (const float4*)(x + (size_t)nodeBase * FIN_);
        float4* xs4 = (float4*)xs;
        for (int i = tid; i < 32 * FIN_ / 4; i += 256) xs4[i] = x4[i];
        __syncthreads();

        int d = tid & 31, ns = tid >> 5;
        for (int rep = 0; rep < 4; ++rep) {
            int node = ns + rep * 8;
            float acc = 0.f;
#pragma unroll 4
            for (int k = 0; k < FIN_; ++k) acc += xs[node * FIN_ + k] * wsm[k * DIM_ + d];
            yh[(size_t)(nodeBase + node) * DIM_ + d] = __float2bfloat16(acc);
        }
    }
}

// ---------------------------------------------------------------------------
// Gather: 4 lanes x 16B (uint4) per 64B row -> 16 nodes per wave (good
// Poisson load balance), 4-wide unroll. 8 float accumulators per lane.
// ---------------------------------------------------------------------------
__device__ __forceinline__ void gather_row4(const int* __restrict__ csr,
                                            const char* __restrict__ vb,
                                            int beg, int end, int loff, float* acc) {
    int i = beg;
    for (; i + 3 < end; i += 4) {
        int s0 = csr[i], s1 = csr[i + 1], s2 = csr[i + 2], s3 = csr[i + 3];
        uint4 u0 = *(const uint4*)(vb + (((size_t)s0) << 6) + loff);
        uint4 u1 = *(const uint4*)(vb + (((size_t)s1) << 6) + loff);
        uint4 u2 = *(const uint4*)(vb + (((size_t)s2) << 6) + loff);
        uint4 u3 = *(const uint4*)(vb + (((size_t)s3) << 6) + loff);
        acc[0] += (bflo(u0.x) + bflo(u1.x)) + (bflo(u2.x) + bflo(u3.x));
        acc[1] += (bfhi(u0.x) + bfhi(u1.x)) + (bfhi(u2.x) + bfhi(u3.x));
        acc[2] += (bflo(u0.y) + bflo(u1.y)) + (bflo(u2.y) + bflo(u3.y));
        acc[3] += (bfhi(u0.y) + bfhi(u1.y)) + (bfhi(u2.y) + bfhi(u3.y));
        acc[4] += (bflo(u0.z) + bflo(u1.z)) + (bflo(u2.z) + bflo(u3.z));
        acc[5] += (bfhi(u0.z) + bfhi(u1.z)) + (bfhi(u2.z) + bfhi(u3.z));
        acc[6] += (bflo(u0.w) + bflo(u1.w)) + (bflo(u2.w) + bflo(u3.w));
        acc[7] += (bfhi(u0.w) + bfhi(u1.w)) + (bfhi(u2.w) + bfhi(u3.w));
    }
    for (; i < end; ++i) {
        int s0 = csr[i];
        uint4 u0 = *(const uint4*)(vb + (((size_t)s0) << 6) + loff);
        acc[0] += bflo(u0.x); acc[1] += bfhi(u0.x);
        acc[2] += bflo(u0.y); acc[3] += bfhi(u0.y);
        acc[4] += bflo(u0.z); acc[5] += bfhi(u0.z);
        acc[6] += bflo(u0.w); acc[7] += bfhi(u0.w);
    }
}

// ---------------------------------------------------------------------------
// Fused 1: 64 nodes/block, single LDS buffer A (in-place phase updates via
// register staging). gather -> u=relu(agg+y+b1a) -> hb=bn1(relu(u@w1b+b1b))
// -> zh=bf16(hb@w2a) written straight from registers.
// LDS: A 8448 + w1s/w2s 8192 = 16.6 KB -> 8 blocks/CU (wave-capped).
// ---------------------------------------------------------------------------
__global__ __launch_bounds__(256) void aggmlp1_kernel(const int* __restrict__ offs,
                                                      const int* __restrict__ csr,
                                                      const __hip_bfloat16* __restrict__ yh,
                                                      const float* __restrict__ b1a,
                                                      const float* __restrict__ w1b,
                                                      const float* __restrict__ b1b,
                                                      const float* __restrict__ g1,
                                                      const float* __restrict__ be1,
                                                      const float* __restrict__ m1,
                                                      const float* __restrict__ v1,
                                                      const float* __restrict__ w2a,
                                                      __hip_bfloat16* __restrict__ zh) {
    __shared__ float A[64 * 33];
    __shared__ float w1s[DIM_ * DIM_];
    __shared__ float w2s[DIM_ * DIM_];
    int tid = threadIdx.x;
    for (int i = tid; i < DIM_ * DIM_; i += 256) { w1s[i] = w1b[i]; w2s[i] = w2a[i]; }

    // --- gather phase: 4 lanes x 16B per node, 64 nodes/block ---
    int nl = tid >> 2, lane = tid & 3;
    int node = blockIdx.x * 64 + nl;
    int beg = 0, end = 0;
    if (node < N_) { beg = offs[node]; end = offs[node + 1]; }
    float acc[8] = {0.f, 0.f, 0.f, 0.f, 0.f, 0.f, 0.f, 0.f};
    gather_row4(csr, (const char*)yh, beg, end, lane << 4, acc);
    {
        float* p = &A[nl * 33 + lane * 8];
#pragma unroll
        for (int j = 0; j < 8; ++j) p[j] = acc[j];
    }
    __syncthreads();

    int d = tid & 31, ng = tid >> 5;
    size_t gbase = (size_t)blockIdx.x * 64 * DIM_;

    // u = relu(agg + y + b1a)   (each element owned by one thread)
#pragma unroll
    for (int r = 0; r < 8; ++r) {
        int n = r * 8 + ng;
        if (blockIdx.x * 64 + n < N_) {
            float yv = __bfloat162float(yh[gbase + n * DIM_ + d]);
            A[n * 33 + d] = fmaxf(A[n * 33 + d] + yv + b1a[d], 0.f);
        }
    }
    __syncthreads();

    float sc1 = g1[d] * rsqrtf(v1[d] + 1e-5f);
    float sh1 = be1[d] - m1[d] * sc1;

    // hb = bn1(relu(u @ w1b + b1b)) -> registers, then in-place over A
    float hb[8];
#pragma unroll
    for (int r = 0; r < 8; ++r) {
        int n = r * 8 + ng;
        float s = b1b[d];
#pragma unroll
        for (int k = 0; k < DIM_; ++k) s += A[n * 33 + k] * w1s[k * DIM_ + d];
        hb[r] = fmaxf(s, 0.f) * sc1 + sh1;
    }
    __syncthreads();
#pragma unroll
    for (int r = 0; r < 8; ++r) A[(r * 8 + ng) * 33 + d] = hb[r];
    __syncthreads();

    // z = hb @ w2a -> bf16 global, straight from registers
#pragma unroll
    for (int r = 0; r < 8; ++r) {
        int n = r * 8 + ng;
        float s = 0.f;
#pragma unroll
        for (int k = 0; k < DIM_; ++k) s += A[n * 33 + k] * w2s[k * DIM_ + d];
        if (blockIdx.x * 64 + n < N_) zh[gbase + n * DIM_ + d] = __float2bfloat16(s);
    }
}

// ---------------------------------------------------------------------------
// Fused 2: same single-buffer structure; wC overwrites dead wA/wB space.
// gather -> u2=relu(agg+z+b2a) -> hb=bn2(u2@w2b+b2b) -> f=relu(hb@fc1w+f1b)
// -> logits=f@fc2w+f2b -> log_softmax -> out.
// LDS: A 8448 + w2[2048 floats] 8192 = 16.6 KB.
// ---------------------------------------------------------------------------
__global__ __launch_bounds__(256) void aggmlp2_kernel(const int* __restrict__ offs,
                                                      const int* __restrict__ csr,
                                                      const __hip_bfloat16* __restrict__ zh,
                                                      const float* __restrict__ b2a,
                                                      const float* __restrict__ w2b,
                                                      const float* __restrict__ b2b,
                                                      const float* __restrict__ g2,
                                                      const float* __restrict__ be2,
                                                      const float* __restrict__ m2,
                                                      const float* __restrict__ v2,
                                                      const float* __restrict__ f1w,
                                                      const float* __restrict__ f1b,
                                                      const float* __restrict__ f2w,
                                                      const float* __restrict__ f2b,
                                                      float* __restrict__ out) {
    __shared__ float A[64 * 33];
    __shared__ float w2[2 * DIM_ * DIM_];   // wA | wB; later reused for wC (1280 <= 2048)
    int tid = threadIdx.x;
    for (int i = tid; i < DIM_ * DIM_; i += 256) { w2[i] = w2b[i]; w2[DIM_ * DIM_ + i] = f1w[i]; }

    // --- gather phase ---
    int nl = tid >> 2, lane = tid & 3;
    int node = blockIdx.x * 64 + nl;
    int beg = 0, end = 0;
    if (node < N_) { beg = offs[node]; end = offs[node + 1]; }
    float acc[8] = {0.f, 0.f, 0.f, 0.f, 0.f, 0.f, 0.f, 0.f};
    gather_row4(csr, (const char*)zh, beg, end, lane << 4, acc);
    {
        float* p = &A[nl * 33 + lane * 8];
#pragma unroll
        for (int j = 0; j < 8; ++j) p[j] = acc[j];
    }
    __syncthreads();

    int d = tid & 31, ng = tid >> 5;
    size_t gbase = (size_t)blockIdx.x * 64 * DIM_;

    // u2 = relu(agg + z + b2a)
#pragma unroll
    for (int r = 0; r < 8; ++r) {
        int n = r * 8 + ng;
        if (blockIdx.x * 64 + n < N_) {
            float zv = __bfloat162float(zh[gbase + n * DIM_ + d]);
            A[n * 33 + d] = fmaxf(A[n * 33 + d] + zv + b2a[d], 0.f);
        }
    }
    __syncthreads();

    float sc2 = g2[d] * rsqrtf(v2[d] + 1e-5f);
    float sh2 = be2[d] - m2[d] * sc2;

    // hb = bn2(u2 @ w2b + b2b)  (no relu between conv2 and bn2)
    float t[8];
#pragma unroll
    for (int r = 0; r < 8; ++r) {
        int n = r * 8 + ng;
        float s = b2b[d];
#pragma unroll
        for (int k = 0; k < DIM_; ++k) s += A[n * 33 + k] * w2[k * DIM_ + d];
        t[r] = s * sc2 + sh2;
    }
    __syncthreads();
#pragma unroll
    for (int r = 0; r < 8; ++r) A[(r * 8 + ng) * 33 + d] = t[r];
    __syncthreads();

    // f = relu(hb @ fc1w + fc1b)
#pragma unroll
    for (int r = 0; r < 8; ++r) {
        int n = r * 8 + ng;
        float s = f1b[d];
#pragma unroll
        for (int k = 0; k < DIM_; ++k) s += A[n * 33 + k] * w2[DIM_ * DIM_ + k * DIM_ + d];
        t[r] = fmaxf(s, 0.f);
    }
    __syncthreads();               // all threads done reading wB and A(hb)
#pragma unroll
    for (int r = 0; r < 8; ++r) A[(r * 8 + ng) * 33 + d] = t[r];
    for (int i = tid; i < DIM_ * NC_; i += 256) w2[i] = f2w[i];   // wC over dead wA/wB
    __syncthreads();

    // logits + log_softmax (thread d owns col d and col 32+(d&7))
    int c2 = 32 + (d & 7);
#pragma unroll
    for (int r = 0; r < 8; ++r) {
        int n = r * 8 + ng;
        float l0 = f2b[d];
        float l1 = f2b[c2];
#pragma unroll
        for (int k = 0; k < DIM_; ++k) {
            float fv = A[n * 33 + k];
            l0 += fv * w2[k * NC_ + d];
            l1 += fv * w2[k * NC_ + c2];
        }
        float mx = fmaxf(l0, l1);
#pragma unroll
        for (int off = 16; off; off >>= 1) mx = fmaxf(mx, __shfl_xor(mx, off));
        float se = __expf(l0 - mx) + ((d < 8) ? __expf(l1 - mx) : 0.f);
#pragma unroll
        for (int off = 16; off; off >>= 1) se += __shfl_xor(se, off);
        float lse = mx + __logf(se);
        int gn = blockIdx.x * 64 + n;
        if (gn < N_) {
            size_t ob = (size_t)gn * NC_;
            out[ob + d] = l0 - lse;
            if (d < 8) out[ob + 32 + d] = l1 - lse;
        }
    }
}

// ---------------------------------------------------------------------------
extern "C" void kernel_launch(void* const* d_in, const int* in_sizes, int n_in,
                              void* d_out, int out_size, void* d_ws, size_t ws_size,
                              hipStream_t stream) {
    const float* x   = (const float*)d_in[0];
    const void*  edg = d_in[1];
    const float* w1a = (const float*)d_in[2];
    const float* b1a = (const float*)d_in[3];
    const float* w1b = (const float*)d_in[4];
    const float* b1b = (const float*)d_in[5];
    const float* w2a = (const float*)d_in[6];
    const float* b2a = (const float*)d_in[7];
    const float* w2b = (const float*)d_in[8];
    const float* b2b = (const float*)d_in[9];
    const float* g1  = (const float*)d_in[10];
    const float* be1 = (const float*)d_in[11];
    const float* m1  = (const float*)d_in[12];
    const float* v1  = (const float*)d_in[13];
    const float* g2  = (const float*)d_in[14];
    const float* be2 = (const float*)d_in[15];
    const float* m2  = (const float*)d_in[16];
    const float* v2  = (const float*)d_in[17];
    const float* f1w = (const float*)d_in[18];
    const float* f1b = (const float*)d_in[19];
    const float* f2w = (const float*)d_in[20];
    const float* f2b = (const float*)d_in[21];
    float* out = (float*)d_out;

    // Workspace layout (byte offsets, 128B-aligned)
    char* ws = (char*)d_ws;
    int* done   = (int*)ws;                      // 4 B (memset each launch)
    int* bcnt   = (int*)(ws + 256);              // 782 ints (pad 3328)
    int* bbase  = (int*)(ws + 3584);             // 782 ints (pad 3328)
    int* ghist  = (int*)(ws + 6912);             // 256*782 ints
    int* gcurT  = (int*)(ws + 807680);           // 782*256 ints
    int* offs   = (int*)(ws + 1608448);          // N+1 ints (pad 400128)
    int* packed = (int*)(ws + 2008576);          // E ints
    int* csr    = (int*)(ws + 8408576);          // E ints
    __hip_bfloat16* yh = (__hip_bfloat16*)(ws + 14808576);  // N*DIM bf16
    __hip_bfloat16* zh = (__hip_bfloat16*)(ws + 21208576);  // N*DIM bf16

    hipMemsetAsync(done, 0, 4, stream);

    // ---- Build per-node CSR (deterministic, no global atomics) ----
    chist_kernel<<<NCHUNK, 256, 0, stream>>>(edg, ghist);
    colscan_kernel<<<NB_BKT, 256, 0, stream>>>(ghist, gcurT, bcnt, bbase, offs, done);
    dscatter_kernel<<<NCHUNK, 256, 0, stream>>>(edg, bbase, gcurT, packed);
    fat_kernel<<<NB_BKT + PROJ_NB, 256, 0, stream>>>(bcnt, bbase, packed, offs, csr,
                                                     x, w1a, yh);

    // ---- Layer 1 (proj folded pre-aggregation) ----
    aggmlp1_kernel<<<(N_ + 63) / 64, 256, 0, stream>>>(offs, csr, yh, b1a, w1b, b1b,
                                                       g1, be1, m1, v1, w2a, zh);

    // ---- Layer 2 + head (w2a folded pre-aggregation) ----
    aggmlp2_kernel<<<(N_ + 63) / 64, 256, 0, stream>>>(offs, csr, zh, b2a, w2b, b2b,
                                                       g2, be2, m2, v2, f1w, f1b,
                                                       f2w, f2b, out);
}

// Round 9
// 324.532 us; speedup vs baseline: 1.1321x; 1.1098x over previous
//
#include <hip/hip_runtime.h>
#include <hip/hip_bf16.h>

// Problem constants
static constexpr int N_   = 100000;
static constexpr int E_   = 1600000;
static constexpr int FIN_ = 128;
static constexpr int DIM_ = 32;
static constexpr int NC_  = 40;
static constexpr int NB_BKT = (N_ + 127) / 128;   // 782 buckets of 128 dst nodes
static constexpr int NCHUNK = 256;                // edge chunks
static constexpr int EPC    = E_ / NCHUNK;        // 6250 edges per chunk (exact)
static constexpr int PROJ_NB = N_ / 32;           // 3125 proj blocks
static constexpr int CS_NB  = (NB_BKT + 7) / 8;   // 98 colscan blocks

__device__ __forceinline__ int edge_at(const void* e, int is64, long long i) {
    return is64 ? (int)((const long long*)e)[i] : ((const int*)e)[i];
}

__device__ __forceinline__ float bflo(unsigned u) { return __uint_as_float(u << 16); }
__device__ __forceinline__ float bfhi(unsigned u) { return __uint_as_float(u & 0xffff0000u); }

// Per-block edge dtype detection (reference says int64; JAX x64-off gives int32;
// int32 read as int64 -> garbage high words -> out of [0,N) w.h.p.)
#define DETECT_FLAG(edge, sflag)                                        \
    if (threadIdx.x < 64) {                                             \
        const long long* p_ = (const long long*)(edge);                 \
        long long v_ = p_[threadIdx.x];                                 \
        bool bad_ = (v_ < 0 || v_ >= (long long)N_);                    \
        unsigned long long m_ = __ballot(bad_);                         \
        if (threadIdx.x == 0) sflag = (m_ == 0ull) ? 1 : 0;             \
    }                                                                   \
    __syncthreads();

// ---------------------------------------------------------------------------
// Build 1: per-chunk bucket histogram in LDS -> ghist[b][k] (coalesced write)
// ---------------------------------------------------------------------------
__global__ __launch_bounds__(256) void chist_kernel(const void* __restrict__ edge,
                                                    int* __restrict__ ghist) {
    __shared__ int lh[NB_BKT];
    __shared__ int sflag;
    DETECT_FLAG(edge, sflag)
    for (int i = threadIdx.x; i < NB_BKT; i += 256) lh[i] = 0;
    __syncthreads();
    int f = sflag;
    int b = blockIdx.x;
    int end = b * EPC + EPC;
    for (int e = b * EPC + threadIdx.x; e < end; e += 256) {
        int d = edge_at(edge, f, (long long)E_ + e);
        atomicAdd(&lh[d >> 7], 1);           // LDS int atomic
    }
    __syncthreads();
    for (int i = threadIdx.x; i < NB_BKT; i += 256) ghist[b * NB_BKT + i] = lh[i];
}

// ---------------------------------------------------------------------------
// Build 2: column scans, 8 buckets per block via coalesced LDS tile.
// Outputs gcur[b][k] (CHUNK-major -> dscatter reads a coalesced row) and
// bcnt[k]. Last block (ticket) scans bucket totals -> bbase + offs[N].
// ---------------------------------------------------------------------------
__global__ __launch_bounds__(256) void colscan_kernel(const int* __restrict__ ghist,
                                                      int* __restrict__ gcur,
                                                      int* __restrict__ bcnt,
                                                      int* __restrict__ bbase,
                                                      int* __restrict__ offs,
                                                      int* __restrict__ done) {
    __shared__ int tile[256 * 9];   // [chunk b][bucket kk], padded
    __shared__ int a[256];
    __shared__ int lastFlag;
    int tid = threadIdx.x;
    int k0 = blockIdx.x * 8;

    // coalesced-ish load: 8 lanes per chunk-row (32B of one line), 32 rows/pass
    {
        int kk = tid & 7, r0 = tid >> 3;
        for (int p = 0; p < 8; ++p) {
            int b = r0 + p * 32;
            int k = k0 + kk;
            tile[b * 9 + kk] = (k < NB_BKT) ? ghist[b * NB_BKT + k] : 0;
        }
    }
    __syncthreads();

    // scan each of 8 columns over 256 chunks: half-wave (32 lanes) per column,
    // 8 chunks per lane, shuffle-scan of lane sums.
    int c = tid >> 5, lane = tid & 31;
    int v[8]; int s = 0;
#pragma unroll
    for (int r = 0; r < 8; ++r) { v[r] = tile[(lane * 8 + r) * 9 + c]; s += v[r]; }
    int incl = s;
#pragma unroll
    for (int off = 1; off < 32; off <<= 1) {
        int u = __shfl_up(incl, off, 32);
        if (lane >= off) incl += u;
    }
    int ex = incl - s;
    int k = k0 + c;
    if (k < NB_BKT) {
        int run = ex;
#pragma unroll
        for (int r = 0; r < 8; ++r) {
            int b = lane * 8 + r;
            gcur[b * NB_BKT + k] = run;     // exclusive prefix for (chunk b, bucket k)
            run += v[r];
        }
        if (lane == 31) bcnt[k] = run;      // bucket total
    }
    __syncthreads();
    if (tid == 0) {
        __threadfence();                    // release gcur/bcnt before ticket
        int old = atomicAdd(done, 1);
        lastFlag = (old == CS_NB - 1) ? 1 : 0;
    }
    __syncthreads();
    if (lastFlag) {
        __threadfence();                    // acquire other blocks' bcnt
        int b4[4]; int base4 = tid * 4; int t = 0;
#pragma unroll
        for (int j = 0; j < 4; ++j) { int i = base4 + j; b4[j] = (i < NB_BKT) ? bcnt[i] : 0; t += b4[j]; }
        a[tid] = t;
        __syncthreads();
        for (int off = 1; off < 256; off <<= 1) {
            int u = a[tid] + ((tid >= off) ? a[tid - off] : 0);
            __syncthreads(); a[tid] = u; __syncthreads();
        }
        int g = a[tid] - t;
#pragma unroll
        for (int j = 0; j < 4; ++j) { int i = base4 + j; if (i < NB_BKT) bbase[i] = g; g += b4[j]; }
        if (tid == 255) offs[N_] = a[255];  // == E_
    }
}

// ---------------------------------------------------------------------------
// Build 3: deterministic scatter into bucket regions; cursors in LDS.
// Cursor init is a coalesced 3 KB row read (gcur is chunk-major).
// ---------------------------------------------------------------------------
__global__ __launch_bounds__(256) void dscatter_kernel(const void* __restrict__ edge,
                                                       const int* __restrict__ bbase,
                                                       const int* __restrict__ gcur,
                                                       int* __restrict__ packed) {
    __shared__ int cur[NB_BKT];
    __shared__ int sflag;
    DETECT_FLAG(edge, sflag)
    int b = blockIdx.x, tid = threadIdx.x;
    for (int k = tid; k < NB_BKT; k += 256) cur[k] = bbase[k] + gcur[b * NB_BKT + k];
    __syncthreads();
    int f = sflag;
    int end = b * EPC + EPC;
    for (int e = b * EPC + tid; e < end; e += 256) {
        int s = edge_at(edge, f, e);
        int d = edge_at(edge, f, (long long)E_ + e);
        int pos = atomicAdd(&cur[d >> 7], 1);     // LDS int atomic
        packed[pos] = s | ((d & 127) << 17);      // N < 2^17
    }
}

// ---------------------------------------------------------------------------
// Build 4 ∥ proj: blocks [0,782): per-bucket counting sort -> offs[] + csr[];
// blocks [782, 782+3125): yh = bf16(x @ w1a). Independent work, one dispatch.
// ---------------------------------------------------------------------------
__global__ __launch_bounds__(256) void fat_kernel(const int* __restrict__ bcnt,
                                                  const int* __restrict__ bbase,
                                                  const int* __restrict__ packed,
                                                  int* __restrict__ offs,
                                                  int* __restrict__ csr,
                                                  const float* __restrict__ x,
                                                  const float* __restrict__ w,
                                                  __hip_bfloat16* __restrict__ yh) {
    __shared__ __align__(16) char smem[32768];
    int tid = threadIdx.x;
    if (blockIdx.x < NB_BKT) {
        // ---- bsort ----
        int* c   = (int*)smem;
        int* cur = (int*)smem + 128;
        int b = blockIdx.x;
        int beg = bbase[b], cnt = bcnt[b];
        if (tid < 128) c[tid] = 0;
        __syncthreads();
        for (int i = tid; i < cnt; i += 256)
            atomicAdd(&c[packed[beg + i] >> 17], 1);
        __syncthreads();
        int myv = (tid < 128) ? c[tid] : 0;
        for (int off = 1; off < 128; off <<= 1) {
            int t = 0;
            if (tid < 128) t = c[tid] + ((tid >= off) ? c[tid - off] : 0);
            __syncthreads();
            if (tid < 128) c[tid] = t;
            __syncthreads();
        }
        if (tid < 128) {
            int ex = c[tid] - myv;
            cur[tid] = ex;
            int node = b * 128 + tid;
            if (node < N_) offs[node] = beg + ex;
        }
        __syncthreads();
        for (int i = tid; i < cnt; i += 256) {
            int v = packed[beg + i];
            int p = atomicAdd(&cur[v >> 17], 1);
            csr[beg + p] = v & 0x1FFFF;
        }
    } else {
        // ---- proj1: 32 nodes per block ----
        float* wsm = (float*)smem;               // 16 KB
        float* xs  = (float*)(smem + 16384);     // 16 KB
        const float4* w4 = (const float4*)w;
        float4* ws4 = (float4*)wsm;
        for (int i = tid; i < FIN_ * DIM_ / 4; i += 256) ws4[i] = w4[i];

        int nodeBase = (blockIdx.x - NB_BKT) * 32;
        const float4* x4 = (const float4*)(x + (size_t)nodeBase * FIN_);
        float4* xs4 = (float4*)xs;
        for (int i = tid; i < 32 * FIN_ / 4; i += 256) xs4[i] = x4[i];
        __syncthreads();

        int d = tid & 31, ns = tid >> 5;
        for (int rep = 0; rep < 4; ++rep) {
            int node = ns + rep * 8;
            float acc = 0.f;
#pragma unroll 4
            for (int k = 0; k < FIN_; ++k) acc += xs[node * FIN_ + k] * wsm[k * DIM_ + d];
            yh[(size_t)(nodeBase + node) * DIM_ + d] = __float2bfloat16(acc);
        }
    }
}

// ---------------------------------------------------------------------------
// Gather (R6-proven config): 8 lanes x 8B (uint2) per 64B row, 4-wide unroll.
// ---------------------------------------------------------------------------
__device__ __forceinline__ void gather_row(const int* __restrict__ csr,
                                           const char* __restrict__ vb,
                                           int beg, int end, int loff,
                                           float& a0, float& a1, float& a2, float& a3) {
    int i = beg;
    for (; i + 3 < end; i += 4) {
        int s0 = csr[i], s1 = csr[i + 1], s2 = csr[i + 2], s3 = csr[i + 3];
        uint2 u0 = *(const uint2*)(vb + (((size_t)s0) << 6) + loff);
        uint2 u1 = *(const uint2*)(vb + (((size_t)s1) << 6) + loff);
        uint2 u2 = *(const uint2*)(vb + (((size_t)s2) << 6) + loff);
        uint2 u3 = *(const uint2*)(vb + (((size_t)s3) << 6) + loff);
        a0 += (bflo(u0.x) + bflo(u1.x)) + (bflo(u2.x) + bflo(u3.x));
        a1 += (bfhi(u0.x) + bfhi(u1.x)) + (bfhi(u2.x) + bfhi(u3.x));
        a2 += (bflo(u0.y) + bflo(u1.y)) + (bflo(u2.y) + bflo(u3.y));
        a3 += (bfhi(u0.y) + bfhi(u1.y)) + (bfhi(u2.y) + bfhi(u3.y));
    }
    for (; i < end; ++i) {
        int s0 = csr[i];
        uint2 u0 = *(const uint2*)(vb + (((size_t)s0) << 6) + loff);
        a0 += bflo(u0.x); a1 += bfhi(u0.x); a2 += bflo(u0.y); a3 += bfhi(u0.y);
    }
}

// ---------------------------------------------------------------------------
// Fused 1 (R6-proven): 32 nodes/block, dual A/B LDS buffers.
// gather -> u=relu(agg+y+b1a) -> hb=bn1(relu(u@w1b+b1b)) -> zh=bf16(hb@w2a).
// ---------------------------------------------------------------------------
__global__ __launch_bounds__(256) void aggmlp1_kernel(const int* __restrict__ offs,
                                                      const int* __restrict__ csr,
                                                      const __hip_bfloat16* __restrict__ yh,
                                                      const float* __restrict__ b1a,
                                                      const float* __restrict__ w1b,
                                                      const float* __restrict__ b1b,
                                                      const float* __restrict__ g1,
                                                      const float* __restrict__ be1,
                                                      const float* __restrict__ m1,
                                                      const float* __restrict__ v1,
                                                      const float* __restrict__ w2a,
                                                      __hip_bfloat16* __restrict__ zh) {
    __shared__ float A[32 * 33];
    __shared__ float B[32 * 33];
    __shared__ float w1s[DIM_ * DIM_];
    __shared__ float w2s[DIM_ * DIM_];
    int tid = threadIdx.x;
    for (int i = tid; i < DIM_ * DIM_; i += 256) { w1s[i] = w1b[i]; w2s[i] = w2a[i]; }

    int nl = tid >> 3, lane = tid & 7;
    int node = blockIdx.x * 32 + nl;
    int beg = offs[node], end = offs[node + 1];
    float a0 = 0.f, a1 = 0.f, a2 = 0.f, a3 = 0.f;
    gather_row(csr, (const char*)yh, beg, end, lane << 3, a0, a1, a2, a3);
    {
        float* p = &A[nl * 33 + lane * 4];
        p[0] = a0; p[1] = a1; p[2] = a2; p[3] = a3;
    }
    __syncthreads();

    int d = tid & 31, ng = tid >> 5;
    size_t gbase = (size_t)blockIdx.x * 32 * DIM_;

    // u = relu(agg + y + b1a)
#pragma unroll
    for (int r = 0; r < 4; ++r) {
        int n = r * 8 + ng;
        float yv = __bfloat162float(yh[gbase + n * DIM_ + d]);
        A[n * 33 + d] = fmaxf(A[n * 33 + d] + yv + b1a[d], 0.f);
    }
    __syncthreads();

    float sc1 = g1[d] * rsqrtf(v1[d] + 1e-5f);
    float sh1 = be1[d] - m1[d] * sc1;

    // hb = bn1(relu(u @ w1b + b1b))
#pragma unroll
    for (int r = 0; r < 4; ++r) {
        int n = r * 8 + ng;
        float s = b1b[d];
#pragma unroll
        for (int k = 0; k < DIM_; ++k) s += A[n * 33 + k] * w1s[k * DIM_ + d];
        B[n * 33 + d] = fmaxf(s, 0.f) * sc1 + sh1;
    }
    __syncthreads();

    // z = hb @ w2a -> bf16
#pragma unroll
    for (int r = 0; r < 4; ++r) {
        int n = r * 8 + ng;
        float s = 0.f;
#pragma unroll
        for (int k = 0; k < DIM_; ++k) s += B[n * 33 + k] * w2s[k * DIM_ + d];
        zh[gbase + n * DIM_ + d] = __float2bfloat16(s);
    }
}

// ---------------------------------------------------------------------------
// Fused 2 (R6-proven): gather -> u=relu(agg+z+b2a) -> hb=bn2(u@w2b+b2b) ->
// f=relu(hb@fc1w+f1b) -> logits -> log_softmax. wC loads over dead B.
// ---------------------------------------------------------------------------
__global__ __launch_bounds__(256) void aggmlp2_kernel(const int* __restrict__ offs,
                                                      const int* __restrict__ csr,
                                                      const __hip_bfloat16* __restrict__ zh,
                                                      const float* __restrict__ b2a,
                                                      const float* __restrict__ w2b,
                                                      const float* __restrict__ b2b,
                                                      const float* __restrict__ g2,
                                                      const float* __restrict__ be2,
                                                      const float* __restrict__ m2,
                                                      const float* __restrict__ v2,
                                                      const float* __restrict__ f1w,
                                                      const float* __restrict__ f1b,
                                                      const float* __restrict__ f2w,
                                                      const float* __restrict__ f2b,
                                                      float* __restrict__ out) {
    __shared__ float A[32 * 33];
    __shared__ float BC[DIM_ * NC_];   // B (hb, 1056 floats) then wC (1280 floats)
    __shared__ float wA[DIM_ * DIM_];
    __shared__ float wB[DIM_ * DIM_];
    int tid = threadIdx.x;
    for (int i = tid; i < DIM_ * DIM_; i += 256) { wA[i] = w2b[i]; wB[i] = f1w[i]; }

    int nl = tid >> 3, lane = tid & 7;
    int node = blockIdx.x * 32 + nl;
    int beg = offs[node], end = offs[node + 1];
    float a0 = 0.f, a1 = 0.f, a2 = 0.f, a3 = 0.f;
    gather_row(csr, (const char*)zh, beg, end, lane << 3, a0, a1, a2, a3);
    {
        float* p = &A[nl * 33 + lane * 4];
        p[0] = a0; p[1] = a1; p[2] = a2; p[3] = a3;
    }
    __syncthreads();

    int d = tid & 31, ng = tid >> 5;
    size_t gbase = (size_t)blockIdx.x * 32 * DIM_;

    // u2 = relu(agg + z + b2a)
#pragma unroll
    for (int r = 0; r < 4; ++r) {
        int n = r * 8 + ng;
        float zv = __bfloat162float(zh[gbase + n * DIM_ + d]);
        A[n * 33 + d] = fmaxf(A[n * 33 + d] + zv + b2a[d], 0.f);
    }
    __syncthreads();

    float sc2 = g2[d] * rsqrtf(v2[d] + 1e-5f);
    float sh2 = be2[d] - m2[d] * sc2;

    // hb = bn2(u2 @ w2b + b2b)   (no relu between conv2 and bn2)
#pragma unroll
    for (int r = 0; r < 4; ++r) {
        int n = r * 8 + ng;
        float s = b2b[d];
#pragma unroll
        for (int k = 0; k < DIM_; ++k) s += A[n * 33 + k] * wA[k * DIM_ + d];
        BC[n * 33 + d] = s * sc2 + sh2;
    }
    __syncthreads();

    // f = relu(hb @ fc1w + fc1b) -> overwrite A
#pragma unroll
    for (int r = 0; r < 4; ++r) {
        int n = r * 8 + ng;
        float s = f1b[d];
#pragma unroll
        for (int k = 0; k < DIM_; ++k) s += BC[n * 33 + k] * wB[k * DIM_ + d];
        A[n * 33 + d] = fmaxf(s, 0.f);
    }
    __syncthreads();
    // B dead -> load wC
    for (int i = tid; i < DIM_ * NC_; i += 256) BC[i] = f2w[i];
    __syncthreads();

    // logits + log_softmax (thread d owns col d and col 32+(d&7))
    int c2 = 32 + (d & 7);
#pragma unroll
    for (int r = 0; r < 4; ++r) {
        int n = r * 8 + ng;
        float l0 = f2b[d];
        float l1 = f2b[c2];
#pragma unroll
        for (int k = 0; k < DIM_; ++k) {
            float fv = A[n * 33 + k];
            l0 += fv * BC[k * NC_ + d];
            l1 += fv * BC[k * NC_ + c2];
        }
        float mx = fmaxf(l0, l1);
#pragma unroll
        for (int off = 16; off; off >>= 1) mx = fmaxf(mx, __shfl_xor(mx, off));
        float se = __expf(l0 - mx) + ((d < 8) ? __expf(l1 - mx) : 0.f);
#pragma unroll
        for (int off = 16; off; off >>= 1) se += __shfl_xor(se, off);
        float lse = mx + __logf(se);
        size_t ob = (size_t)(blockIdx.x * 32 + n) * NC_;
        out[ob + d] = l0 - lse;
        if (d < 8) out[ob + 32 + d] = l1 - lse;
    }
}

// ---------------------------------------------------------------------------
extern "C" void kernel_launch(void* const* d_in, const int* in_sizes, int n_in,
                              void* d_out, int out_size, void* d_ws, size_t ws_size,
                              hipStream_t stream) {
    const float* x   = (const float*)d_in[0];
    const void*  edg = d_in[1];
    const float* w1a = (const float*)d_in[2];
    const float* b1a = (const float*)d_in[3];
    const float* w1b = (const float*)d_in[4];
    const float* b1b = (const float*)d_in[5];
    const float* w2a = (const float*)d_in[6];
    const float* b2a = (const float*)d_in[7];
    const float* w2b = (const float*)d_in[8];
    const float* b2b = (const float*)d_in[9];
    const float* g1  = (const float*)d_in[10];
    const float* be1 = (const float*)d_in[11];
    const float* m1  = (const float*)d_in[12];
    const float* v1  = (const float*)d_in[13];
    const float* g2  = (const float*)d_in[14];
    const float* be2 = (const float*)d_in[15];
    const float* m2  = (const float*)d_in[16];
    const float* v2  = (const float*)d_in[17];
    const float* f1w = (const float*)d_in[18];
    const float* f1b = (const float*)d_in[19];
    const float* f2w = (const float*)d_in[20];
    const float* f2b = (const float*)d_in[21];
    float* out = (float*)d_out;

    // Workspace layout (byte offsets, 128B-aligned)
    char* ws = (char*)d_ws;
    int* done   = (int*)ws;                      // 4 B (memset each launch)
    int* bcnt   = (int*)(ws + 256);              // 782 ints (pad 3328)
    int* bbase  = (int*)(ws + 3584);             // 782 ints (pad 3328)
    int* ghist  = (int*)(ws + 6912);             // 256*782 ints
    int* gcur   = (int*)(ws + 807680);           // 256*782 ints (chunk-major)
    int* offs   = (int*)(ws + 1608448);          // N+1 ints (pad 400128)
    int* packed = (int*)(ws + 2008576);          // E ints
    int* csr    = (int*)(ws + 8408576);          // E ints
    __hip_bfloat16* yh = (__hip_bfloat16*)(ws + 14808576);  // N*DIM bf16
    __hip_bfloat16* zh = (__hip_bfloat16*)(ws + 21208576);  // N*DIM bf16

    hipMemsetAsync(done, 0, 4, stream);

    // ---- Build per-node CSR (deterministic, no global atomics) ----
    chist_kernel<<<NCHUNK, 256, 0, stream>>>(edg, ghist);
    colscan_kernel<<<CS_NB, 256, 0, stream>>>(ghist, gcur, bcnt, bbase, offs, done);
    dscatter_kernel<<<NCHUNK, 256, 0, stream>>>(edg, bbase, gcur, packed);
    fat_kernel<<<NB_BKT + PROJ_NB, 256, 0, stream>>>(bcnt, bbase, packed, offs, csr,
                                                     x, w1a, yh);

    // ---- Layer 1 (proj folded pre-aggregation) ----
    aggmlp1_kernel<<<N_ / 32, 256, 0, stream>>>(offs, csr, yh, b1a, w1b, b1b,
                                                g1, be1, m1, v1, w2a, zh);

    // ---- Layer 2 + head (w2a folded pre-aggregation) ----
    aggmlp2_kernel<<<N_ / 32, 256, 0, stream>>>(offs, csr, zh, b2a, w2b, b2b,
                                                g2, be2, m2, v2, f1w, f1b,
                                                f2w, f2b, out);
}